// Round 4
// baseline (635.026 us; speedup 1.0000x reference)
//
#include <hip/hip_runtime.h>

#define EPSF  1e-8f
#define IMG_W 512
#define IMG_H 512
#define HWPX  (IMG_W*IMG_H)
#define NB    32

// Gaussian 7-tap weights, sigma = 7/6, normalized (matches np float32 pipeline)
#define GW0 0.0125602730f
#define GW1 0.0788280293f
#define GW2 0.2372963577f
#define GW3 0.3426321149f

#define RCPF(x)  __builtin_amdgcn_rcpf(x)
#define SQRTF(x) __builtin_amdgcn_sqrtf(x)
#define LOG2F(x) __builtin_amdgcn_logf(x)
#define EXP2F(x) __builtin_amdgcn_exp2f(x)

// ws layout: minb[NB] | maxb[NB] | sdsum[NB] | cand[3*NB]

// ---------------- init ----------------
__global__ void k_init(unsigned* __restrict__ minb, unsigned* __restrict__ maxb,
                       float* __restrict__ sdsum, float* __restrict__ cand) {
  int t = threadIdx.x;
  if (t < NB) { minb[t] = 0x7F7FFFFFu; maxb[t] = 0u; sdsum[t] = 0.f; }
  if (t < 3*NB) cand[t] = 0.f;
}

// ---------------- pass 1: per-sample min/max of grayscale(D) ----------------
// 128 chunks x NB blocks; each thread: 2 float4 per plane, 6 independent loads.
__global__ __launch_bounds__(256) void k_minmax(const float* __restrict__ D,
                                                unsigned* __restrict__ minb,
                                                unsigned* __restrict__ maxb) {
  const int b = blockIdx.y, chunk = blockIdx.x, tid = threadIdx.x;
  const float4* P0 = (const float4*)(D + (size_t)b * 3 * HWPX);
  const float4* P1 = P0 + HWPX/4;
  const float4* P2 = P1 + HWPX/4;
  const int i0 = chunk * 512 + tid;
  const int i1 = i0 + 256;
  float4 a0 = P0[i0], c0 = P1[i0], e0 = P2[i0];
  float4 a1 = P0[i1], c1 = P1[i1], e1 = P2[i1];
  float mn = __uint_as_float(0x7F7FFFFFu), mx = 0.f;
  float g;
  g = 0.2989f*a0.x + 0.587f*c0.x + 0.114f*e0.x; mn = fminf(mn,g); mx = fmaxf(mx,g);
  g = 0.2989f*a0.y + 0.587f*c0.y + 0.114f*e0.y; mn = fminf(mn,g); mx = fmaxf(mx,g);
  g = 0.2989f*a0.z + 0.587f*c0.z + 0.114f*e0.z; mn = fminf(mn,g); mx = fmaxf(mx,g);
  g = 0.2989f*a0.w + 0.587f*c0.w + 0.114f*e0.w; mn = fminf(mn,g); mx = fmaxf(mx,g);
  g = 0.2989f*a1.x + 0.587f*c1.x + 0.114f*e1.x; mn = fminf(mn,g); mx = fmaxf(mx,g);
  g = 0.2989f*a1.y + 0.587f*c1.y + 0.114f*e1.y; mn = fminf(mn,g); mx = fmaxf(mx,g);
  g = 0.2989f*a1.z + 0.587f*c1.z + 0.114f*e1.z; mn = fminf(mn,g); mx = fmaxf(mx,g);
  g = 0.2989f*a1.w + 0.587f*c1.w + 0.114f*e1.w; mn = fminf(mn,g); mx = fmaxf(mx,g);
  #pragma unroll
  for (int o = 32; o > 0; o >>= 1) {
    mn = fminf(mn, __shfl_down(mn, o, 64));
    mx = fmaxf(mx, __shfl_down(mx, o, 64));
  }
  __shared__ float smn[4], smx[4];
  if ((tid & 63) == 0) { smn[tid>>6] = mn; smx[tid>>6] = mx; }
  __syncthreads();
  if (tid == 0) {
    mn = fminf(fminf(smn[0],smn[1]), fminf(smn[2],smn[3]));
    mx = fmaxf(fmaxf(smx[0],smx[1]), fmaxf(smx[2],smx[3]));
    atomicMin(minb + b, __float_as_uint(mn));   // non-negative: uint order == float order
    atomicMax(maxb + b, __float_as_uint(mx));
  }
}

// ---------------- pass 2: fused MSCN + Sobel + maps; 3 candidate sums + SD sum ----------------
#define TW 64
#define TH 32
#define HALO 3
#define SWP 72            // staged width: left pad 4 (aligned), covers [tx0-4, tx0+68)
#define SH  38            // TH + 6
#define NCHUNK (SH*18)    // float4 chunks per plane

__global__ __launch_bounds__(256, 4) void k_main(const float* __restrict__ D, const float* __restrict__ R,
                                                 const unsigned* __restrict__ minb,
                                                 const unsigned* __restrict__ maxb,
                                                 float* __restrict__ sdsum,
                                                 float* __restrict__ cand) {
  __shared__ float sDg[SH][SWP];
  __shared__ float sRg[SH][SWP];
  __shared__ float sSD[TH][TW];
  __shared__ float sSC[TH][TW];

  const int tid = threadIdx.x;
  const int b   = blockIdx.z;
  const int tx0 = blockIdx.x * TW;
  const int ty0 = blockIdx.y * TH;

  const float dr = __uint_as_float(maxb[b]) - __uint_as_float(minb[b]);
  const float CM = (0.01f*dr)*(0.01f*dr);
  const float CD = 0.5f*CM;
  const float CG = (0.03f*dr)*(0.03f*dr);
  const float CC = 0.5f*CG;

  const float* D0 = D + (size_t)b*3*HWPX;
  const float* R0 = R + (size_t)b*3*HWPX;
  const float4* fD0 = (const float4*)D0;
  const float4* fD1 = fD0 + HWPX/4;
  const float4* fD2 = fD1 + HWPX/4;
  const float4* fR0 = (const float4*)R0;
  const float4* fR1 = fR0 + HWPX/4;
  const float4* fR2 = fR1 + HWPX/4;

  float sdacc = 0.f;

  // ---- staging: whole-float4 chunks; OOB chunks are always entirely OOB ----
  const int cx0 = tx0 - 4;              // multiple of 4
  for (int j = tid; j < NCHUNK; j += 256) {
    const int r  = j / 18;
    const int c  = j - r*18;
    const int gy = ty0 - HALO + r;
    const int gx = cx0 + c*4;
    float4 dg4 = make_float4(0.f,0.f,0.f,0.f);
    float4 rg4 = make_float4(0.f,0.f,0.f,0.f);
    if ((unsigned)gy < IMG_H && gx >= 0 && gx < IMG_W) {
      const int o4 = gy*(IMG_W/4) + (gx >> 2);
      float4 d0 = fD0[o4], d1 = fD1[o4], d2 = fD2[o4];
      float4 r0 = fR0[o4], r1 = fR1[o4], r2 = fR2[o4];
      dg4.x = 0.2989f*d0.x + 0.587f*d1.x + 0.114f*d2.x;
      dg4.y = 0.2989f*d0.y + 0.587f*d1.y + 0.114f*d2.y;
      dg4.z = 0.2989f*d0.z + 0.587f*d1.z + 0.114f*d2.z;
      dg4.w = 0.2989f*d0.w + 0.587f*d1.w + 0.114f*d2.w;
      rg4.x = 0.2989f*r0.x + 0.587f*r1.x + 0.114f*r2.x;
      rg4.y = 0.2989f*r0.y + 0.587f*r1.y + 0.114f*r2.y;
      rg4.z = 0.2989f*r0.z + 0.587f*r1.z + 0.114f*r2.z;
      rg4.w = 0.2989f*r0.w + 0.587f*r1.w + 0.114f*r2.w;
      if (r >= HALO && r < HALO+TH && c >= 1 && c <= 16) {
        float4 sd4, sc4;
        #define MAPS(f) { \
          float dmn = fminf(fminf(d0.f,d1.f),d2.f); \
          float rmn = fminf(fminf(r0.f,r1.f),r2.f); \
          float a_ = dmn*(1.f/255.f), c_ = rmn*(1.f/255.f); \
          float sd = (2.f*a_*c_ + CD) * RCPF(a_*a_ + c_*c_ + CD + EPSF); \
          sd4.f = sd; sdacc += sd; \
          float dmx = fmaxf(fmaxf(d0.f,d1.f),d2.f); \
          float rmx = fmaxf(fmaxf(r0.f,r1.f),r2.f); \
          float dcol = ((dmx-dmn+EPSF) * RCPF(dmx+EPSF)) * dmx; \
          float rcol = ((rmx-rmn+EPSF) * RCPF(rmx+EPSF)) * rmx; \
          sc4.f = (2.f*dcol*rcol + CC) * RCPF(dcol*dcol + rcol*rcol + CC + EPSF); }
        MAPS(x) MAPS(y) MAPS(z) MAPS(w)
        #undef MAPS
        *(float4*)&sSD[r-HALO][(c-1)*4] = sd4;
        *(float4*)&sSC[r-HALO][(c-1)*4] = sc4;
      }
    }
    *(float4*)&sDg[r][c*4] = dg4;
    *(float4*)&sRg[r][c*4] = rg4;
  }
  __syncthreads();

  // ---- separable conv, per-column rolling windows of horizontal partials ----
  const int x   = tid & 63;
  const int yo0 = (tid >> 6) * 8;

  float whgD[7]={0}, whqD[7]={0}, whgR[7]={0}, whqR[7]={0};  // gauss: g, g^2
  float wsxD[5]={0}, wsyD[5]={0}, wsxR[5]={0}, wsyR[5]={0};  // sobel row partials
  float a0 = 0.f, a1 = 0.f, a2 = 0.f;

  #pragma unroll
  for (int step = 0; step < 14; ++step) {
    const int r = yo0 + step;
    float vD[7], vR[7];
    #pragma unroll
    for (int j = 0; j < 7; ++j) { vD[j] = sDg[r][x+1+j]; vR[j] = sRg[r][x+1+j]; }
    float hgD, hqD, hgR, hqR;
    hgD = GW0*(vD[0]+vD[6]) + GW1*(vD[1]+vD[5]) + GW2*(vD[2]+vD[4]) + GW3*vD[3];
    hgR = GW0*(vR[0]+vR[6]) + GW1*(vR[1]+vR[5]) + GW2*(vR[2]+vR[4]) + GW3*vR[3];
    hqD = GW0*(vD[0]*vD[0]+vD[6]*vD[6]) + GW1*(vD[1]*vD[1]+vD[5]*vD[5])
        + GW2*(vD[2]*vD[2]+vD[4]*vD[4]) + GW3*vD[3]*vD[3];
    hqR = GW0*(vR[0]*vR[0]+vR[6]*vR[6]) + GW1*(vR[1]*vR[1]+vR[5]*vR[5])
        + GW2*(vR[2]*vR[2]+vR[4]*vR[4]) + GW3*vR[3]*vR[3];
    float sxD = vD[2]-vD[4], syD = vD[2]+2.f*vD[3]+vD[4];
    float sxR = vR[2]-vR[4], syR = vR[2]+2.f*vR[3]+vR[4];
    #pragma unroll
    for (int j = 0; j < 6; ++j) {
      whgD[j]=whgD[j+1]; whqD[j]=whqD[j+1]; whgR[j]=whgR[j+1]; whqR[j]=whqR[j+1];
    }
    whgD[6]=hgD; whqD[6]=hqD; whgR[6]=hgR; whqR[6]=hqR;
    #pragma unroll
    for (int j = 0; j < 4; ++j) {
      wsxD[j]=wsxD[j+1]; wsyD[j]=wsyD[j+1]; wsxR[j]=wsxR[j+1]; wsyR[j]=wsyR[j+1];
    }
    wsxD[4]=sxD; wsyD[4]=syD; wsxR[4]=sxR; wsyR[4]=syR;

    if (step >= 6) {
      const int yo = yo0 + step - 6;
      float muD, exD, muR, exR;
      muD = GW0*(whgD[0]+whgD[6]) + GW1*(whgD[1]+whgD[5]) + GW2*(whgD[2]+whgD[4]) + GW3*whgD[3];
      exD = GW0*(whqD[0]+whqD[6]) + GW1*(whqD[1]+whqD[5]) + GW2*(whqD[2]+whqD[4]) + GW3*whqD[3];
      muR = GW0*(whgR[0]+whgR[6]) + GW1*(whgR[1]+whgR[5]) + GW2*(whgR[2]+whgR[4]) + GW3*whgR[3];
      exR = GW0*(whqR[0]+whqR[6]) + GW1*(whqR[1]+whqR[5]) + GW2*(whqR[2]+whqR[4]) + GW3*whqR[3];
      float v0D = sDg[yo+HALO][x+4];
      float v0R = sRg[yo+HALO][x+4];
      float sigD = SQRTF(fabsf(exD - muD*muD + EPSF));
      float sigR = SQRTF(fabsf(exR - muR*muR + EPSF));
      float Dm = (v0D - muD) * RCPF(sigD + EPSF);
      float Rm = (v0R - muR) * RCPF(sigR + EPSF);
      float SM = (2.f*Dm*Rm + CM) * RCPF(Dm*Dm + Rm*Rm + CM);
      // sobel: h-rows yo+2, yo+3, yo+4 -> 5-deep window idx 0,1,2
      float gxD = wsxD[0] + 2.f*wsxD[1] + wsxD[2];
      float gyD = wsyD[0] - wsyD[2];
      float gxR = wsxR[0] + 2.f*wsxR[1] + wsxR[2];
      float gyR = wsyR[0] - wsyR[2];
      float GD = SQRTF(gxD*gxD + gyD*gyD + EPSF);
      float GR = SQRTF(gxR*gxR + gyR*gyR + EPSF);
      float SG = (2.f*GD*GR + CG) * RCPF(GD*GD + GR*GR + CG + EPSF);
      float SDv = sSD[yo][x];
      float SCv = sSC[yo][x];
      float m1 = fabsf(SM * SDv);
      float m2 = SG * SCv;
      float l1 = LOG2F(m1);            // m1==0 -> -inf -> exp2 -> 0, matches power(0,b)
      float l2 = LOG2F(m2);
      a0 += EXP2F(0.2f*l1 + 0.8f*l2);
      a1 += EXP2F(0.8f*l1 + 0.2f*l2);
      a2 += EXP2F(0.5f*l1 + 0.5f*l2);
    }
  }

  // ---- block reduce, one atomic per accumulator ----
  #pragma unroll
  for (int o = 32; o > 0; o >>= 1) {
    sdacc += __shfl_down(sdacc, o, 64);
    a0    += __shfl_down(a0,    o, 64);
    a1    += __shfl_down(a1,    o, 64);
    a2    += __shfl_down(a2,    o, 64);
  }
  __shared__ float red[4][4];
  const int w = tid >> 6;
  if ((tid & 63) == 0) { red[w][0]=sdacc; red[w][1]=a0; red[w][2]=a1; red[w][3]=a2; }
  __syncthreads();
  if (tid < 4) {
    float t = red[0][tid]+red[1][tid]+red[2][tid]+red[3][tid];
    if (tid == 0) atomicAdd(sdsum + b, t);
    else          atomicAdd(cand + (tid-1)*NB + b, t);
  }
}

// ---------------- pass 3: select candidate per sample, batch mean ----------------
__global__ void k_final(const float* __restrict__ sdsum, const float* __restrict__ cand,
                        float* __restrict__ out) {
  const int t = threadIdx.x;
  float v = 0.f;
  if (t < NB) {
    float meanSD = sdsum[t] * (1.f/(float)HWPX);
    float c;
    if      (meanSD > 0.85f && meanSD <= 1.0f)  c = cand[0*NB + t];
    else if (meanSD >= 0.f  && meanSD <= 0.85f) c = cand[1*NB + t];
    else                                        c = cand[2*NB + t];
    v = c;
  }
  #pragma unroll
  for (int o = 32; o > 0; o >>= 1) v += __shfl_down(v, o, 64);
  if (t == 0) out[0] = v * (1.f/8388608.f);   // 1/(B*H*W) = 2^-23
}

extern "C" void kernel_launch(void* const* d_in, const int* in_sizes, int n_in,
                              void* d_out, int out_size, void* d_ws, size_t ws_size,
                              hipStream_t stream) {
  (void)in_sizes; (void)n_in; (void)out_size; (void)ws_size;
  const float* D = (const float*)d_in[0];
  const float* R = (const float*)d_in[1];
  float* out = (float*)d_out;
  unsigned* minb  = (unsigned*)d_ws;
  unsigned* maxb  = minb + NB;
  float*    sdsum = (float*)(maxb + NB);
  float*    cand  = sdsum + NB;

  k_init  <<<1, 128, 0, stream>>>(minb, maxb, sdsum, cand);
  k_minmax<<<dim3(128, NB), 256, 0, stream>>>(D, minb, maxb);
  k_main  <<<dim3(IMG_W/TW, IMG_H/TH, NB), 256, 0, stream>>>(D, R, minb, maxb, sdsum, cand);
  k_final <<<1, 64, 0, stream>>>(sdsum, cand, out);
}

// Round 6
// 330.823 us; speedup vs baseline: 1.9195x; 1.9195x over previous
//
#include <hip/hip_runtime.h>

#define EPSF  1e-8f
#define IMG_W 512
#define IMG_H 512
#define HWPX  (IMG_W*IMG_H)
#define NB    32

// Gaussian 7-tap weights, sigma = 7/6, normalized (matches np float32 pipeline)
#define GW0 0.0125602730f
#define GW1 0.0788280293f
#define GW2 0.2372963577f
#define GW3 0.3426321149f

#define RCPF(x)  __builtin_amdgcn_rcpf(x)
#define SQRTF(x) __builtin_amdgcn_sqrtf(x)
#define LOG2F(x) __builtin_amdgcn_logf(x)
#define EXP2F(x) __builtin_amdgcn_exp2f(x)

// ws layout: minb[NB] | maxb[NB] | sdsum[NB] | cand[3*NB]

// ---------------- init ----------------
__global__ void k_init(unsigned* __restrict__ minb, unsigned* __restrict__ maxb,
                       float* __restrict__ sdsum, float* __restrict__ cand) {
  int t = threadIdx.x;
  if (t < NB) { minb[t] = 0x7F7FFFFFu; maxb[t] = 0u; sdsum[t] = 0.f; }
  if (t < 3*NB) cand[t] = 0.f;
}

// ---------------- pass 1: per-sample min/max of grayscale(D) ----------------
__global__ __launch_bounds__(256) void k_minmax(const float* __restrict__ D,
                                                unsigned* __restrict__ minb,
                                                unsigned* __restrict__ maxb) {
  const int b = blockIdx.y, chunk = blockIdx.x, tid = threadIdx.x;
  const float4* P0 = (const float4*)(D + (size_t)b * 3 * HWPX);
  const float4* P1 = P0 + HWPX/4;
  const float4* P2 = P1 + HWPX/4;
  const int i0 = chunk * 512 + tid;
  const int i1 = i0 + 256;
  float4 a0 = P0[i0], c0 = P1[i0], e0 = P2[i0];
  float4 a1 = P0[i1], c1 = P1[i1], e1 = P2[i1];
  float mn = __uint_as_float(0x7F7FFFFFu), mx = 0.f;
  float g;
  g = 0.2989f*a0.x + 0.587f*c0.x + 0.114f*e0.x; mn = fminf(mn,g); mx = fmaxf(mx,g);
  g = 0.2989f*a0.y + 0.587f*c0.y + 0.114f*e0.y; mn = fminf(mn,g); mx = fmaxf(mx,g);
  g = 0.2989f*a0.z + 0.587f*c0.z + 0.114f*e0.z; mn = fminf(mn,g); mx = fmaxf(mx,g);
  g = 0.2989f*a0.w + 0.587f*c0.w + 0.114f*e0.w; mn = fminf(mn,g); mx = fmaxf(mx,g);
  g = 0.2989f*a1.x + 0.587f*c1.x + 0.114f*e1.x; mn = fminf(mn,g); mx = fmaxf(mx,g);
  g = 0.2989f*a1.y + 0.587f*c1.y + 0.114f*e1.y; mn = fminf(mn,g); mx = fmaxf(mx,g);
  g = 0.2989f*a1.z + 0.587f*c1.z + 0.114f*e1.z; mn = fminf(mn,g); mx = fmaxf(mx,g);
  g = 0.2989f*a1.w + 0.587f*c1.w + 0.114f*e1.w; mn = fminf(mn,g); mx = fmaxf(mx,g);
  #pragma unroll
  for (int o = 32; o > 0; o >>= 1) {
    mn = fminf(mn, __shfl_down(mn, o, 64));
    mx = fmaxf(mx, __shfl_down(mx, o, 64));
  }
  __shared__ float smn[4], smx[4];
  if ((tid & 63) == 0) { smn[tid>>6] = mn; smx[tid>>6] = mx; }
  __syncthreads();
  if (tid == 0) {
    mn = fminf(fminf(smn[0],smn[1]), fminf(smn[2],smn[3]));
    mx = fmaxf(fmaxf(smx[0],smx[1]), fmaxf(smx[2],smx[3]));
    atomicMin(minb + b, __float_as_uint(mn));   // non-negative: uint order == float order
    atomicMax(maxb + b, __float_as_uint(mx));
  }
}

// ---------------- pass 2: fused MSCN + Sobel + maps; 3 candidate sums + SD sum ----------------
#define TW 64
#define TH 32
#define HALO 3
#define SWP 72            // staged width: left pad 4 (aligned), covers [tx0-4, tx0+68)
#define SH  38            // TH + 6
#define NCHUNK (SH*18)    // float4 chunks per plane

// NOTE: no min-waves clause — (256,4) capped VGPR at 64 and spilled ~900 MB
// to scratch (round-4 counters: WRITE_SIZE 922 MB, VALUBusy 13%). Plain
// (256) measured 124 VGPR, zero spill in round 2.
__global__ __launch_bounds__(256) void k_main(const float* __restrict__ D, const float* __restrict__ R,
                                              const unsigned* __restrict__ minb,
                                              const unsigned* __restrict__ maxb,
                                              float* __restrict__ sdsum,
                                              float* __restrict__ cand) {
  __shared__ float sDg[SH][SWP];
  __shared__ float sRg[SH][SWP];
  __shared__ float sSD[TH][TW];
  __shared__ float sSC[TH][TW];

  const int tid = threadIdx.x;
  const int b   = blockIdx.z;
  const int tx0 = blockIdx.x * TW;
  const int ty0 = blockIdx.y * TH;

  const float dr = __uint_as_float(maxb[b]) - __uint_as_float(minb[b]);
  const float CM = (0.01f*dr)*(0.01f*dr);
  const float CD = 0.5f*CM;
  const float CG = (0.03f*dr)*(0.03f*dr);
  const float CC = 0.5f*CG;

  const float* D0 = D + (size_t)b*3*HWPX;
  const float* R0 = R + (size_t)b*3*HWPX;
  const float4* fD0 = (const float4*)D0;
  const float4* fD1 = fD0 + HWPX/4;
  const float4* fD2 = fD1 + HWPX/4;
  const float4* fR0 = (const float4*)R0;
  const float4* fR1 = fR0 + HWPX/4;
  const float4* fR2 = fR1 + HWPX/4;

  float sdacc = 0.f;

  // ---- staging: whole-float4 chunks; OOB chunks are always entirely OOB ----
  const int cx0 = tx0 - 4;              // multiple of 4
  for (int j = tid; j < NCHUNK; j += 256) {
    const int r  = j / 18;
    const int c  = j - r*18;
    const int gy = ty0 - HALO + r;
    const int gx = cx0 + c*4;
    float4 dg4 = make_float4(0.f,0.f,0.f,0.f);
    float4 rg4 = make_float4(0.f,0.f,0.f,0.f);
    if ((unsigned)gy < IMG_H && gx >= 0 && gx < IMG_W) {
      const int o4 = gy*(IMG_W/4) + (gx >> 2);
      float4 d0 = fD0[o4], d1 = fD1[o4], d2 = fD2[o4];
      float4 r0 = fR0[o4], r1 = fR1[o4], r2 = fR2[o4];
      dg4.x = 0.2989f*d0.x + 0.587f*d1.x + 0.114f*d2.x;
      dg4.y = 0.2989f*d0.y + 0.587f*d1.y + 0.114f*d2.y;
      dg4.z = 0.2989f*d0.z + 0.587f*d1.z + 0.114f*d2.z;
      dg4.w = 0.2989f*d0.w + 0.587f*d1.w + 0.114f*d2.w;
      rg4.x = 0.2989f*r0.x + 0.587f*r1.x + 0.114f*r2.x;
      rg4.y = 0.2989f*r0.y + 0.587f*r1.y + 0.114f*r2.y;
      rg4.z = 0.2989f*r0.z + 0.587f*r1.z + 0.114f*r2.z;
      rg4.w = 0.2989f*r0.w + 0.587f*r1.w + 0.114f*r2.w;
      if (r >= HALO && r < HALO+TH && c >= 1 && c <= 16) {
        float4 sd4, sc4;
        #define MAPS(f) { \
          float dmn = fminf(fminf(d0.f,d1.f),d2.f); \
          float rmn = fminf(fminf(r0.f,r1.f),r2.f); \
          float a_ = dmn*(1.f/255.f), c_ = rmn*(1.f/255.f); \
          float sd = (2.f*a_*c_ + CD) * RCPF(a_*a_ + c_*c_ + CD + EPSF); \
          sd4.f = sd; sdacc += sd; \
          float dmx = fmaxf(fmaxf(d0.f,d1.f),d2.f); \
          float rmx = fmaxf(fmaxf(r0.f,r1.f),r2.f); \
          float dcol = ((dmx-dmn+EPSF) * RCPF(dmx+EPSF)) * dmx; \
          float rcol = ((rmx-rmn+EPSF) * RCPF(rmx+EPSF)) * rmx; \
          sc4.f = (2.f*dcol*rcol + CC) * RCPF(dcol*dcol + rcol*rcol + CC + EPSF); }
        MAPS(x) MAPS(y) MAPS(z) MAPS(w)
        #undef MAPS
        *(float4*)&sSD[r-HALO][(c-1)*4] = sd4;
        *(float4*)&sSC[r-HALO][(c-1)*4] = sc4;
      }
    }
    *(float4*)&sDg[r][c*4] = dg4;
    *(float4*)&sRg[r][c*4] = rg4;
  }
  __syncthreads();

  // ---- separable conv, per-column rolling windows of horizontal partials ----
  const int x   = tid & 63;
  const int yo0 = (tid >> 6) * 8;

  float whgD[7]={0}, whqD[7]={0}, whgR[7]={0}, whqR[7]={0};  // gauss: g, g^2
  float wsxD[5]={0}, wsyD[5]={0}, wsxR[5]={0}, wsyR[5]={0};  // sobel row partials
  float a0 = 0.f, a1 = 0.f, a2 = 0.f;

  #pragma unroll
  for (int step = 0; step < 14; ++step) {
    const int r = yo0 + step;
    float vD[7], vR[7];
    #pragma unroll
    for (int j = 0; j < 7; ++j) { vD[j] = sDg[r][x+1+j]; vR[j] = sRg[r][x+1+j]; }
    float hgD, hqD, hgR, hqR;
    hgD = GW0*(vD[0]+vD[6]) + GW1*(vD[1]+vD[5]) + GW2*(vD[2]+vD[4]) + GW3*vD[3];
    hgR = GW0*(vR[0]+vR[6]) + GW1*(vR[1]+vR[5]) + GW2*(vR[2]+vR[4]) + GW3*vR[3];
    hqD = GW0*(vD[0]*vD[0]+vD[6]*vD[6]) + GW1*(vD[1]*vD[1]+vD[5]*vD[5])
        + GW2*(vD[2]*vD[2]+vD[4]*vD[4]) + GW3*vD[3]*vD[3];
    hqR = GW0*(vR[0]*vR[0]+vR[6]*vR[6]) + GW1*(vR[1]*vR[1]+vR[5]*vR[5])
        + GW2*(vR[2]*vR[2]+vR[4]*vR[4]) + GW3*vR[3]*vR[3];
    float sxD = vD[2]-vD[4], syD = vD[2]+2.f*vD[3]+vD[4];
    float sxR = vR[2]-vR[4], syR = vR[2]+2.f*vR[3]+vR[4];
    #pragma unroll
    for (int j = 0; j < 6; ++j) {
      whgD[j]=whgD[j+1]; whqD[j]=whqD[j+1]; whgR[j]=whgR[j+1]; whqR[j]=whqR[j+1];
    }
    whgD[6]=hgD; whqD[6]=hqD; whgR[6]=hgR; whqR[6]=hqR;
    #pragma unroll
    for (int j = 0; j < 4; ++j) {
      wsxD[j]=wsxD[j+1]; wsyD[j]=wsyD[j+1]; wsxR[j]=wsxR[j+1]; wsyR[j]=wsyR[j+1];
    }
    wsxD[4]=sxD; wsyD[4]=syD; wsxR[4]=sxR; wsyR[4]=syR;

    if (step >= 6) {
      const int yo = yo0 + step - 6;
      float muD, exD, muR, exR;
      muD = GW0*(whgD[0]+whgD[6]) + GW1*(whgD[1]+whgD[5]) + GW2*(whgD[2]+whgD[4]) + GW3*whgD[3];
      exD = GW0*(whqD[0]+whqD[6]) + GW1*(whqD[1]+whqD[5]) + GW2*(whqD[2]+whqD[4]) + GW3*whqD[3];
      muR = GW0*(whgR[0]+whgR[6]) + GW1*(whgR[1]+whgR[5]) + GW2*(whgR[2]+whgR[4]) + GW3*whgR[3];
      exR = GW0*(whqR[0]+whqR[6]) + GW1*(whqR[1]+whqR[5]) + GW2*(whqR[2]+whqR[4]) + GW3*whqR[3];
      float v0D = sDg[yo+HALO][x+4];
      float v0R = sRg[yo+HALO][x+4];
      float sigD = SQRTF(fabsf(exD - muD*muD + EPSF));
      float sigR = SQRTF(fabsf(exR - muR*muR + EPSF));
      float Dm = (v0D - muD) * RCPF(sigD + EPSF);
      float Rm = (v0R - muR) * RCPF(sigR + EPSF);
      float SM = (2.f*Dm*Rm + CM) * RCPF(Dm*Dm + Rm*Rm + CM);
      // sobel: h-rows yo+2, yo+3, yo+4 -> 5-deep window idx 0,1,2
      float gxD = wsxD[0] + 2.f*wsxD[1] + wsxD[2];
      float gyD = wsyD[0] - wsyD[2];
      float gxR = wsxR[0] + 2.f*wsxR[1] + wsxR[2];
      float gyR = wsyR[0] - wsyR[2];
      float GD = SQRTF(gxD*gxD + gyD*gyD + EPSF);
      float GR = SQRTF(gxR*gxR + gyR*gyR + EPSF);
      float SG = (2.f*GD*GR + CG) * RCPF(GD*GD + GR*GR + CG + EPSF);
      float SDv = sSD[yo][x];
      float SCv = sSC[yo][x];
      float m1 = fabsf(SM * SDv);
      float m2 = SG * SCv;
      float l1 = LOG2F(m1);            // m1==0 -> -inf -> exp2 -> 0, matches power(0,b)
      float l2 = LOG2F(m2);
      a0 += EXP2F(0.2f*l1 + 0.8f*l2);
      a1 += EXP2F(0.8f*l1 + 0.2f*l2);
      a2 += EXP2F(0.5f*l1 + 0.5f*l2);
    }
  }

  // ---- block reduce, one atomic per accumulator ----
  #pragma unroll
  for (int o = 32; o > 0; o >>= 1) {
    sdacc += __shfl_down(sdacc, o, 64);
    a0    += __shfl_down(a0,    o, 64);
    a1    += __shfl_down(a1,    o, 64);
    a2    += __shfl_down(a2,    o, 64);
  }
  __shared__ float red[4][4];
  const int w = tid >> 6;
  if ((tid & 63) == 0) { red[w][0]=sdacc; red[w][1]=a0; red[w][2]=a1; red[w][3]=a2; }
  __syncthreads();
  if (tid < 4) {
    float t = red[0][tid]+red[1][tid]+red[2][tid]+red[3][tid];
    if (tid == 0) atomicAdd(sdsum + b, t);
    else          atomicAdd(cand + (tid-1)*NB + b, t);
  }
}

// ---------------- pass 3: select candidate per sample, batch mean ----------------
__global__ void k_final(const float* __restrict__ sdsum, const float* __restrict__ cand,
                        float* __restrict__ out) {
  const int t = threadIdx.x;
  float v = 0.f;
  if (t < NB) {
    float meanSD = sdsum[t] * (1.f/(float)HWPX);
    float c;
    if      (meanSD > 0.85f && meanSD <= 1.0f)  c = cand[0*NB + t];
    else if (meanSD >= 0.f  && meanSD <= 0.85f) c = cand[1*NB + t];
    else                                        c = cand[2*NB + t];
    v = c;
  }
  #pragma unroll
  for (int o = 32; o > 0; o >>= 1) v += __shfl_down(v, o, 64);
  if (t == 0) out[0] = v * (1.f/8388608.f);   // 1/(B*H*W) = 2^-23
}

extern "C" void kernel_launch(void* const* d_in, const int* in_sizes, int n_in,
                              void* d_out, int out_size, void* d_ws, size_t ws_size,
                              hipStream_t stream) {
  (void)in_sizes; (void)n_in; (void)out_size; (void)ws_size;
  const float* D = (const float*)d_in[0];
  const float* R = (const float*)d_in[1];
  float* out = (float*)d_out;
  unsigned* minb  = (unsigned*)d_ws;
  unsigned* maxb  = minb + NB;
  float*    sdsum = (float*)(maxb + NB);
  float*    cand  = sdsum + NB;

  k_init  <<<1, 128, 0, stream>>>(minb, maxb, sdsum, cand);
  k_minmax<<<dim3(128, NB), 256, 0, stream>>>(D, minb, maxb);
  k_main  <<<dim3(IMG_W/TW, IMG_H/TH, NB), 256, 0, stream>>>(D, R, minb, maxb, sdsum, cand);
  k_final <<<1, 64, 0, stream>>>(sdsum, cand, out);
}

// Round 8
// 320.210 us; speedup vs baseline: 1.9832x; 1.0331x over previous
//
#include <hip/hip_runtime.h>

#define EPSF  1e-8f
#define IMG_W 512
#define IMG_H 512
#define HWPX  (IMG_W*IMG_H)
#define NB    32
#define NCHK  128   // minmax chunks per sample

// Gaussian 7-tap weights, sigma = 7/6, normalized (matches np float32 pipeline)
#define GW0 0.0125602730f
#define GW1 0.0788280293f
#define GW2 0.2372963577f
#define GW3 0.3426321149f

#define RCPF(x)  __builtin_amdgcn_rcpf(x)
#define SQRTF(x) __builtin_amdgcn_sqrtf(x)
#define LOG2F(x) __builtin_amdgcn_logf(x)
#define EXP2F(x) __builtin_amdgcn_exp2f(x)

// ws layout (floats): minb[32](u) | maxb[32](u) | sdsum[32] | cand[96] | mnp[4096] | mxp[4096]

// ---------------- init: zero the atomic accumulators ----------------
__global__ void k_init(float* __restrict__ sdsum, float* __restrict__ cand) {
  int t = threadIdx.x;
  if (t < NB) sdsum[t] = 0.f;
  if (t < 3*NB) cand[t] = 0.f;
}

// ---------------- pass 1a: per-block partial min/max of grayscale(D) ----------------
// NO atomics: 4096 same-address atomics serialized ~120+us in rounds 2/6.
__global__ __launch_bounds__(256) void k_minmax(const float* __restrict__ D,
                                                float* __restrict__ mnp,
                                                float* __restrict__ mxp) {
  const int b = blockIdx.y, chunk = blockIdx.x, tid = threadIdx.x;
  const float4* P0 = (const float4*)(D + (size_t)b * 3 * HWPX);
  const float4* P1 = P0 + HWPX/4;
  const float4* P2 = P1 + HWPX/4;
  const int i0 = chunk * 512 + tid;
  const int i1 = i0 + 256;
  float4 a0 = P0[i0], c0 = P1[i0], e0 = P2[i0];
  float4 a1 = P0[i1], c1 = P1[i1], e1 = P2[i1];
  float mn = __uint_as_float(0x7F7FFFFFu), mx = 0.f;   // gray >= 0 always
  float g;
  g = 0.2989f*a0.x + 0.587f*c0.x + 0.114f*e0.x; mn = fminf(mn,g); mx = fmaxf(mx,g);
  g = 0.2989f*a0.y + 0.587f*c0.y + 0.114f*e0.y; mn = fminf(mn,g); mx = fmaxf(mx,g);
  g = 0.2989f*a0.z + 0.587f*c0.z + 0.114f*e0.z; mn = fminf(mn,g); mx = fmaxf(mx,g);
  g = 0.2989f*a0.w + 0.587f*c0.w + 0.114f*e0.w; mn = fminf(mn,g); mx = fmaxf(mx,g);
  g = 0.2989f*a1.x + 0.587f*c1.x + 0.114f*e1.x; mn = fminf(mn,g); mx = fmaxf(mx,g);
  g = 0.2989f*a1.y + 0.587f*c1.y + 0.114f*e1.y; mn = fminf(mn,g); mx = fmaxf(mx,g);
  g = 0.2989f*a1.z + 0.587f*c1.z + 0.114f*e1.z; mn = fminf(mn,g); mx = fmaxf(mx,g);
  g = 0.2989f*a1.w + 0.587f*c1.w + 0.114f*e1.w; mn = fminf(mn,g); mx = fmaxf(mx,g);
  #pragma unroll
  for (int o = 32; o > 0; o >>= 1) {
    mn = fminf(mn, __shfl_down(mn, o, 64));
    mx = fmaxf(mx, __shfl_down(mx, o, 64));
  }
  __shared__ float smn[4], smx[4];
  if ((tid & 63) == 0) { smn[tid>>6] = mn; smx[tid>>6] = mx; }
  __syncthreads();
  if (tid == 0) {
    mn = fminf(fminf(smn[0],smn[1]), fminf(smn[2],smn[3]));
    mx = fmaxf(fmaxf(smx[0],smx[1]), fmaxf(smx[2],smx[3]));
    mnp[b*NCHK + chunk] = mn;
    mxp[b*NCHK + chunk] = mx;
  }
}

// ---------------- pass 1b: reduce 128 partials per sample ----------------
__global__ void k_red(const float* __restrict__ mnp, const float* __restrict__ mxp,
                      unsigned* __restrict__ minb, unsigned* __restrict__ maxb) {
  const int b = blockIdx.x, t = threadIdx.x;   // 128 threads = 2 waves
  float mn = mnp[b*NCHK + t];
  float mx = mxp[b*NCHK + t];
  #pragma unroll
  for (int o = 32; o > 0; o >>= 1) {
    mn = fminf(mn, __shfl_down(mn, o, 64));
    mx = fmaxf(mx, __shfl_down(mx, o, 64));
  }
  __shared__ float smn[2], smx[2];
  if ((t & 63) == 0) { smn[t>>6] = mn; smx[t>>6] = mx; }
  __syncthreads();
  if (t == 0) {
    minb[b] = __float_as_uint(fminf(smn[0], smn[1]));
    maxb[b] = __float_as_uint(fmaxf(smx[0], smx[1]));
  }
}

// ---------------- pass 2: fused MSCN + Sobel + maps; 3 candidate sums + SD sum ----------------
#define TW 64
#define TH 32
#define HALO 3
#define SWP 72            // staged width: left pad 4 (aligned), covers [tx0-4, tx0+68)
#define SH  38            // TH + 6
#define NCHUNK (SH*18)    // float4 chunks per plane

// NOTE: no min-waves clause in __launch_bounds__ — (256,4) forced 64 VGPR and
// spilled ~900 MB to scratch (round 4). Two-pass conv keeps live-set small so
// natural allocation lands <=128 VGPR -> 4 waves/SIMD (round 6's 136 gave 3).
__global__ __launch_bounds__(256) void k_main(const float* __restrict__ D, const float* __restrict__ R,
                                              const unsigned* __restrict__ minb,
                                              const unsigned* __restrict__ maxb,
                                              float* __restrict__ sdsum,
                                              float* __restrict__ cand) {
  __shared__ float sDg[SH][SWP];
  __shared__ float sRg[SH][SWP];
  __shared__ float sSD[TH][TW];
  __shared__ float sSC[TH][TW];

  const int tid = threadIdx.x;
  const int b   = blockIdx.z;
  const int tx0 = blockIdx.x * TW;
  const int ty0 = blockIdx.y * TH;

  const float dr = __uint_as_float(maxb[b]) - __uint_as_float(minb[b]);
  const float CM = (0.01f*dr)*(0.01f*dr);
  const float CD = 0.5f*CM;
  const float CG = (0.03f*dr)*(0.03f*dr);
  const float CC = 0.5f*CG;

  const float4* fD0 = (const float4*)(D + (size_t)b*3*HWPX);
  const float4* fD1 = fD0 + HWPX/4;
  const float4* fD2 = fD1 + HWPX/4;
  const float4* fR0 = (const float4*)(R + (size_t)b*3*HWPX);
  const float4* fR1 = fR0 + HWPX/4;
  const float4* fR2 = fR1 + HWPX/4;

  float sdacc = 0.f;

  // ---- staging: whole-float4 chunks; OOB chunks are always entirely OOB ----
  const int cx0 = tx0 - 4;              // multiple of 4
  for (int j = tid; j < NCHUNK; j += 256) {
    const int r  = j / 18;
    const int c  = j - r*18;
    const int gy = ty0 - HALO + r;
    const int gx = cx0 + c*4;
    float4 dg4 = make_float4(0.f,0.f,0.f,0.f);
    float4 rg4 = make_float4(0.f,0.f,0.f,0.f);
    if ((unsigned)gy < IMG_H && gx >= 0 && gx < IMG_W) {
      const int o4 = gy*(IMG_W/4) + (gx >> 2);
      float4 d0 = fD0[o4], d1 = fD1[o4], d2 = fD2[o4];
      float4 r0 = fR0[o4], r1 = fR1[o4], r2 = fR2[o4];
      dg4.x = 0.2989f*d0.x + 0.587f*d1.x + 0.114f*d2.x;
      dg4.y = 0.2989f*d0.y + 0.587f*d1.y + 0.114f*d2.y;
      dg4.z = 0.2989f*d0.z + 0.587f*d1.z + 0.114f*d2.z;
      dg4.w = 0.2989f*d0.w + 0.587f*d1.w + 0.114f*d2.w;
      rg4.x = 0.2989f*r0.x + 0.587f*r1.x + 0.114f*r2.x;
      rg4.y = 0.2989f*r0.y + 0.587f*r1.y + 0.114f*r2.y;
      rg4.z = 0.2989f*r0.z + 0.587f*r1.z + 0.114f*r2.z;
      rg4.w = 0.2989f*r0.w + 0.587f*r1.w + 0.114f*r2.w;
      if (r >= HALO && r < HALO+TH && c >= 1 && c <= 16) {
        float4 sd4, sc4;
        #define MAPS(f) { \
          float dmn = fminf(fminf(d0.f,d1.f),d2.f); \
          float rmn = fminf(fminf(r0.f,r1.f),r2.f); \
          float a_ = dmn*(1.f/255.f), c_ = rmn*(1.f/255.f); \
          float sd = (2.f*a_*c_ + CD) * RCPF(a_*a_ + c_*c_ + CD + EPSF); \
          sd4.f = sd; sdacc += sd; \
          float dmx = fmaxf(fmaxf(d0.f,d1.f),d2.f); \
          float rmx = fmaxf(fmaxf(r0.f,r1.f),r2.f); \
          float dcol = ((dmx-dmn+EPSF) * RCPF(dmx+EPSF)) * dmx; \
          float rcol = ((rmx-rmn+EPSF) * RCPF(rmx+EPSF)) * rmx; \
          sc4.f = (2.f*dcol*rcol + CC) * RCPF(dcol*dcol + rcol*rcol + CC + EPSF); }
        MAPS(x) MAPS(y) MAPS(z) MAPS(w)
        #undef MAPS
        *(float4*)&sSD[r-HALO][(c-1)*4] = sd4;
        *(float4*)&sSC[r-HALO][(c-1)*4] = sc4;
      }
    }
    *(float4*)&sDg[r][c*4] = dg4;
    *(float4*)&sRg[r][c*4] = rg4;
  }
  __syncthreads();

  const int x   = tid & 63;
  const int yo0 = (tid >> 6) * 8;

  // ================== PASS 1: D image -> nD[8] (MSCN), gD[8] (grad mag) ==================
  float nD[8], gD[8];
  {
    float whg[7]={0,0,0,0,0,0,0}, whq[7]={0,0,0,0,0,0,0};
    float wsx[3]={0,0,0}, wsy[3]={0,0,0};
    #pragma unroll
    for (int st = 0; st < 14; ++st) {
      const int r = yo0 + st;
      float v[7];
      #pragma unroll
      for (int j = 0; j < 7; ++j) v[j] = sDg[r][x+1+j];
      float hg = GW0*(v[0]+v[6]) + GW1*(v[1]+v[5]) + GW2*(v[2]+v[4]) + GW3*v[3];
      float hq = GW0*(v[0]*v[0]+v[6]*v[6]) + GW1*(v[1]*v[1]+v[5]*v[5])
               + GW2*(v[2]*v[2]+v[4]*v[4]) + GW3*v[3]*v[3];
      #pragma unroll
      for (int j = 0; j < 6; ++j) { whg[j]=whg[j+1]; whq[j]=whq[j+1]; }
      whg[6]=hg; whq[6]=hq;
      wsx[0]=wsx[1]; wsx[1]=wsx[2]; wsx[2]=v[2]-v[4];
      wsy[0]=wsy[1]; wsy[1]=wsy[2]; wsy[2]=v[2]+2.f*v[3]+v[4];
      if (st >= 4 && st < 12) {                 // grad for output row st-4
        float gx = wsx[0] + 2.f*wsx[1] + wsx[2];
        float gy = wsy[0] - wsy[2];
        gD[st-4] = SQRTF(gx*gx + gy*gy + EPSF);
      }
      if (st >= 6) {                            // MSCN for output row st-6
        const int k  = st - 6;
        const int ya = yo0 + k;
        float mu = GW0*(whg[0]+whg[6]) + GW1*(whg[1]+whg[5]) + GW2*(whg[2]+whg[4]) + GW3*whg[3];
        float ex = GW0*(whq[0]+whq[6]) + GW1*(whq[1]+whq[5]) + GW2*(whq[2]+whq[4]) + GW3*whq[3];
        float v0 = sDg[ya+HALO][x+4];
        float sig = SQRTF(fabsf(ex - mu*mu + EPSF));
        nD[k] = (v0 - mu) * RCPF(sig + EPSF);
      }
    }
  }

  // ================== PASS 2: R image, combine, accumulate ==================
  float a0 = 0.f, a1 = 0.f, a2 = 0.f;
  {
    float whg[7]={0,0,0,0,0,0,0}, whq[7]={0,0,0,0,0,0,0};
    float wsx[3]={0,0,0}, wsy[3]={0,0,0};
    float grr[2]={0,0};                         // 2-slot grad pipe for R
    #pragma unroll
    for (int st = 0; st < 14; ++st) {
      const int r = yo0 + st;
      float v[7];
      #pragma unroll
      for (int j = 0; j < 7; ++j) v[j] = sRg[r][x+1+j];
      float hg = GW0*(v[0]+v[6]) + GW1*(v[1]+v[5]) + GW2*(v[2]+v[4]) + GW3*v[3];
      float hq = GW0*(v[0]*v[0]+v[6]*v[6]) + GW1*(v[1]*v[1]+v[5]*v[5])
               + GW2*(v[2]*v[2]+v[4]*v[4]) + GW3*v[3]*v[3];
      #pragma unroll
      for (int j = 0; j < 6; ++j) { whg[j]=whg[j+1]; whq[j]=whq[j+1]; }
      whg[6]=hg; whq[6]=hq;
      wsx[0]=wsx[1]; wsx[1]=wsx[2]; wsx[2]=v[2]-v[4];
      wsy[0]=wsy[1]; wsy[1]=wsy[2]; wsy[2]=v[2]+2.f*v[3]+v[4];

      float GRuse = grr[st & 1];                // grad(R) for output st-6 (stored at st-2)

      if (st >= 4 && st < 12) {                 // grad(R) for output st-4
        float gx = wsx[0] + 2.f*wsx[1] + wsx[2];
        float gy = wsy[0] - wsy[2];
        grr[st & 1] = SQRTF(gx*gx + gy*gy + EPSF);
      }

      if (st >= 6) {
        const int k  = st - 6;
        const int ya = yo0 + k;
        float mu = GW0*(whg[0]+whg[6]) + GW1*(whg[1]+whg[5]) + GW2*(whg[2]+whg[4]) + GW3*whg[3];
        float ex = GW0*(whq[0]+whq[6]) + GW1*(whq[1]+whq[5]) + GW2*(whq[2]+whq[4]) + GW3*whq[3];
        float v0 = sRg[ya+HALO][x+4];
        float sig = SQRTF(fabsf(ex - mu*mu + EPSF));
        float Rm = (v0 - mu) * RCPF(sig + EPSF);
        float Dm = nD[k];
        float SM = (2.f*Dm*Rm + CM) * RCPF(Dm*Dm + Rm*Rm + CM);
        float GDv = gD[k];
        float SG = (2.f*GDv*GRuse + CG) * RCPF(GDv*GDv + GRuse*GRuse + CG + EPSF);
        float SDv = sSD[ya][x];
        float SCv = sSC[ya][x];
        float m1 = fabsf(SM * SDv);
        float m2 = SG * SCv;
        float l1 = LOG2F(m1);                   // m1==0 -> -inf -> exp2 -> 0, matches power(0,b)
        float l2 = LOG2F(m2);
        a0 += EXP2F(0.2f*l1 + 0.8f*l2);
        a1 += EXP2F(0.8f*l1 + 0.2f*l2);
        a2 += EXP2F(0.5f*l1 + 0.5f*l2);
      }
    }
  }

  // ---- block reduce, one atomic per accumulator ----
  #pragma unroll
  for (int o = 32; o > 0; o >>= 1) {
    sdacc += __shfl_down(sdacc, o, 64);
    a0    += __shfl_down(a0,    o, 64);
    a1    += __shfl_down(a1,    o, 64);
    a2    += __shfl_down(a2,    o, 64);
  }
  __shared__ float red[4][4];
  const int w = tid >> 6;
  if ((tid & 63) == 0) { red[w][0]=sdacc; red[w][1]=a0; red[w][2]=a1; red[w][3]=a2; }
  __syncthreads();
  if (tid < 4) {
    float t = red[0][tid]+red[1][tid]+red[2][tid]+red[3][tid];
    if (tid == 0) atomicAdd(sdsum + b, t);
    else          atomicAdd(cand + (tid-1)*NB + b, t);
  }
}

// ---------------- pass 3: select candidate per sample, batch mean ----------------
__global__ void k_final(const float* __restrict__ sdsum, const float* __restrict__ cand,
                        float* __restrict__ out) {
  const int t = threadIdx.x;
  float v = 0.f;
  if (t < NB) {
    float meanSD = sdsum[t] * (1.f/(float)HWPX);
    float c;
    if      (meanSD > 0.85f && meanSD <= 1.0f)  c = cand[0*NB + t];
    else if (meanSD >= 0.f  && meanSD <= 0.85f) c = cand[1*NB + t];
    else                                        c = cand[2*NB + t];
    v = c;
  }
  #pragma unroll
  for (int o = 32; o > 0; o >>= 1) v += __shfl_down(v, o, 64);
  if (t == 0) out[0] = v * (1.f/8388608.f);   // 1/(B*H*W) = 2^-23
}

extern "C" void kernel_launch(void* const* d_in, const int* in_sizes, int n_in,
                              void* d_out, int out_size, void* d_ws, size_t ws_size,
                              hipStream_t stream) {
  (void)in_sizes; (void)n_in; (void)out_size; (void)ws_size;
  const float* D = (const float*)d_in[0];
  const float* R = (const float*)d_in[1];
  float* out = (float*)d_out;
  unsigned* minb  = (unsigned*)d_ws;
  unsigned* maxb  = minb + NB;
  float*    sdsum = (float*)(maxb + NB);
  float*    cand  = sdsum + NB;
  float*    mnp   = cand + 3*NB;
  float*    mxp   = mnp + NB*NCHK;

  k_init  <<<1, 128, 0, stream>>>(sdsum, cand);
  k_minmax<<<dim3(NCHK, NB), 256, 0, stream>>>(D, mnp, mxp);
  k_red   <<<NB, 128, 0, stream>>>(mnp, mxp, minb, maxb);
  k_main  <<<dim3(IMG_W/TW, IMG_H/TH, NB), 256, 0, stream>>>(D, R, minb, maxb, sdsum, cand);
  k_final <<<1, 64, 0, stream>>>(sdsum, cand, out);
}

// Round 10
// 306.311 us; speedup vs baseline: 2.0731x; 1.0454x over previous
//
#include <hip/hip_runtime.h>

#define EPSF  1e-8f
#define IMG_W 512
#define IMG_H 512
#define HWPX  (IMG_W*IMG_H)
#define NB    32
#define NCHK  128   // minmax chunks per sample

// Gaussian 7-tap weights, sigma = 7/6, normalized (matches np float32 pipeline)
#define GW0 0.0125602730f
#define GW1 0.0788280293f
#define GW2 0.2372963577f
#define GW3 0.3426321149f

#define RCPF(x)  __builtin_amdgcn_rcpf(x)
#define SQRTF(x) __builtin_amdgcn_sqrtf(x)
#define LOG2F(x) __builtin_amdgcn_logf(x)
#define EXP2F(x) __builtin_amdgcn_exp2f(x)

// ws layout (floats): minb[32](u) | maxb[32](u) | sdsum[32] | cand[96] | mnp[4096] | mxp[4096]

// ---------------- init ----------------
__global__ void k_init(float* __restrict__ sdsum, float* __restrict__ cand) {
  int t = threadIdx.x;
  if (t < NB) sdsum[t] = 0.f;
  if (t < 3*NB) cand[t] = 0.f;
}

// ---------------- pass 1a: per-block partial min/max of grayscale(D) ----------------
__global__ __launch_bounds__(256) void k_minmax(const float* __restrict__ D,
                                                float* __restrict__ mnp,
                                                float* __restrict__ mxp) {
  const int b = blockIdx.y, chunk = blockIdx.x, tid = threadIdx.x;
  const float4* P0 = (const float4*)(D + (size_t)b * 3 * HWPX);
  const float4* P1 = P0 + HWPX/4;
  const float4* P2 = P1 + HWPX/4;
  const int i0 = chunk * 512 + tid;
  const int i1 = i0 + 256;
  float4 a0 = P0[i0], c0 = P1[i0], e0 = P2[i0];
  float4 a1 = P0[i1], c1 = P1[i1], e1 = P2[i1];
  float mn = __uint_as_float(0x7F7FFFFFu), mx = 0.f;   // gray >= 0 always
  float g;
  g = 0.2989f*a0.x + 0.587f*c0.x + 0.114f*e0.x; mn = fminf(mn,g); mx = fmaxf(mx,g);
  g = 0.2989f*a0.y + 0.587f*c0.y + 0.114f*e0.y; mn = fminf(mn,g); mx = fmaxf(mx,g);
  g = 0.2989f*a0.z + 0.587f*c0.z + 0.114f*e0.z; mn = fminf(mn,g); mx = fmaxf(mx,g);
  g = 0.2989f*a0.w + 0.587f*c0.w + 0.114f*e0.w; mn = fminf(mn,g); mx = fmaxf(mx,g);
  g = 0.2989f*a1.x + 0.587f*c1.x + 0.114f*e1.x; mn = fminf(mn,g); mx = fmaxf(mx,g);
  g = 0.2989f*a1.y + 0.587f*c1.y + 0.114f*e1.y; mn = fminf(mn,g); mx = fmaxf(mx,g);
  g = 0.2989f*a1.z + 0.587f*c1.z + 0.114f*e1.z; mn = fminf(mn,g); mx = fmaxf(mx,g);
  g = 0.2989f*a1.w + 0.587f*c1.w + 0.114f*e1.w; mn = fminf(mn,g); mx = fmaxf(mx,g);
  #pragma unroll
  for (int o = 32; o > 0; o >>= 1) {
    mn = fminf(mn, __shfl_down(mn, o, 64));
    mx = fmaxf(mx, __shfl_down(mx, o, 64));
  }
  __shared__ float smn[4], smx[4];
  if ((tid & 63) == 0) { smn[tid>>6] = mn; smx[tid>>6] = mx; }
  __syncthreads();
  if (tid == 0) {
    mn = fminf(fminf(smn[0],smn[1]), fminf(smn[2],smn[3]));
    mx = fmaxf(fmaxf(smx[0],smx[1]), fmaxf(smx[2],smx[3]));
    mnp[b*NCHK + chunk] = mn;
    mxp[b*NCHK + chunk] = mx;
  }
}

// ---------------- pass 1b: reduce partials ----------------
__global__ void k_red(const float* __restrict__ mnp, const float* __restrict__ mxp,
                      unsigned* __restrict__ minb, unsigned* __restrict__ maxb) {
  const int b = blockIdx.x, t = threadIdx.x;   // 128 threads
  float mn = mnp[b*NCHK + t];
  float mx = mxp[b*NCHK + t];
  #pragma unroll
  for (int o = 32; o > 0; o >>= 1) {
    mn = fminf(mn, __shfl_down(mn, o, 64));
    mx = fmaxf(mx, __shfl_down(mx, o, 64));
  }
  __shared__ float smn[2], smx[2];
  if ((t & 63) == 0) { smn[t>>6] = mn; smx[t>>6] = mx; }
  __syncthreads();
  if (t == 0) {
    minb[b] = __float_as_uint(fminf(smn[0], smn[1]));
    maxb[b] = __float_as_uint(fmaxf(smx[0], smx[1]));
  }
}

// ---------------- pass 2: fused MSCN + Sobel + maps ----------------
// TH=16 tile: LDS 20.4 KB (7 blocks/CU by LDS), shorter unrolled loops and
// half the nD/gD state vs TH=32 — aiming VGPR <=128 for 4 waves/SIMD.
#define TW 64
#define TH 16
#define HALO 3
#define SWP 72            // staged width: left pad 4 (aligned), covers [tx0-4, tx0+68)
#define SH  22            // TH + 6
#define NCHUNK (SH*18)    // 396 float4 chunks per plane

// NOTE: no min-waves clause in __launch_bounds__ — (256,4) forced 64 VGPR and
// spilled ~900 MB to scratch (round 4).
__global__ __launch_bounds__(256) void k_main(const float* __restrict__ D, const float* __restrict__ R,
                                              const unsigned* __restrict__ minb,
                                              const unsigned* __restrict__ maxb,
                                              float* __restrict__ sdsum,
                                              float* __restrict__ cand) {
  __shared__ float sDg[SH][SWP];
  __shared__ float sRg[SH][SWP];
  __shared__ float sSD[TH][TW];
  __shared__ float sSC[TH][TW];

  const int tid = threadIdx.x;
  const int b   = blockIdx.z;
  const int tx0 = blockIdx.x * TW;
  const int ty0 = blockIdx.y * TH;

  const float dr = __uint_as_float(maxb[b]) - __uint_as_float(minb[b]);
  const float CM = (0.01f*dr)*(0.01f*dr);
  const float CD = 0.5f*CM;
  const float CG = (0.03f*dr)*(0.03f*dr);
  const float CC = 0.5f*CG;

  const float4* fD0 = (const float4*)(D + (size_t)b*3*HWPX);
  const float4* fD1 = fD0 + HWPX/4;
  const float4* fD2 = fD1 + HWPX/4;
  const float4* fR0 = (const float4*)(R + (size_t)b*3*HWPX);
  const float4* fR1 = fR0 + HWPX/4;
  const float4* fR2 = fR1 + HWPX/4;

  float sdacc = 0.f;

  // ---- staging: D planes first, reduce to (lum, min, max), then R planes ----
  const int cx0 = tx0 - 4;              // multiple of 4
  #pragma unroll
  for (int jj = 0; jj < 2; ++jj) {
    const int j = tid + jj*256;
    if (j >= NCHUNK) break;
    const int r  = j / 18;
    const int c  = j - r*18;
    const int gy = ty0 - HALO + r;
    const int gx = cx0 + c*4;
    float4 dg4 = make_float4(0.f,0.f,0.f,0.f);
    float4 rg4 = make_float4(0.f,0.f,0.f,0.f);
    if ((unsigned)gy < IMG_H && gx >= 0 && gx < IMG_W) {
      const int o4 = gy*(IMG_W/4) + (gx >> 2);
      const bool center = (r >= HALO && r < HALO+TH && c >= 1 && c <= 16);
      float4 dmn4, dmx4;
      {
        float4 d0 = fD0[o4], d1 = fD1[o4], d2 = fD2[o4];
        dg4.x = 0.2989f*d0.x + 0.587f*d1.x + 0.114f*d2.x;
        dg4.y = 0.2989f*d0.y + 0.587f*d1.y + 0.114f*d2.y;
        dg4.z = 0.2989f*d0.z + 0.587f*d1.z + 0.114f*d2.z;
        dg4.w = 0.2989f*d0.w + 0.587f*d1.w + 0.114f*d2.w;
        dmn4.x = fminf(fminf(d0.x,d1.x),d2.x); dmx4.x = fmaxf(fmaxf(d0.x,d1.x),d2.x);
        dmn4.y = fminf(fminf(d0.y,d1.y),d2.y); dmx4.y = fmaxf(fmaxf(d0.y,d1.y),d2.y);
        dmn4.z = fminf(fminf(d0.z,d1.z),d2.z); dmx4.z = fmaxf(fmaxf(d0.z,d1.z),d2.z);
        dmn4.w = fminf(fminf(d0.w,d1.w),d2.w); dmx4.w = fmaxf(fmaxf(d0.w,d1.w),d2.w);
      }
      {
        float4 r0 = fR0[o4], r1 = fR1[o4], r2 = fR2[o4];
        rg4.x = 0.2989f*r0.x + 0.587f*r1.x + 0.114f*r2.x;
        rg4.y = 0.2989f*r0.y + 0.587f*r1.y + 0.114f*r2.y;
        rg4.z = 0.2989f*r0.z + 0.587f*r1.z + 0.114f*r2.z;
        rg4.w = 0.2989f*r0.w + 0.587f*r1.w + 0.114f*r2.w;
        if (center) {
          float4 sd4, sc4;
          #define MAPS(f) { \
            float rmn = fminf(fminf(r0.f,r1.f),r2.f); \
            float rmx = fmaxf(fmaxf(r0.f,r1.f),r2.f); \
            float a_ = dmn4.f*(1.f/255.f), c_ = rmn*(1.f/255.f); \
            float sd = (2.f*a_*c_ + CD) * RCPF(a_*a_ + c_*c_ + CD + EPSF); \
            sd4.f = sd; sdacc += sd; \
            float dcol = ((dmx4.f-dmn4.f+EPSF) * RCPF(dmx4.f+EPSF)) * dmx4.f; \
            float rcol = ((rmx-rmn+EPSF) * RCPF(rmx+EPSF)) * rmx; \
            sc4.f = (2.f*dcol*rcol + CC) * RCPF(dcol*dcol + rcol*rcol + CC + EPSF); }
          MAPS(x) MAPS(y) MAPS(z) MAPS(w)
          #undef MAPS
          *(float4*)&sSD[r-HALO][(c-1)*4] = sd4;
          *(float4*)&sSC[r-HALO][(c-1)*4] = sc4;
        }
      }
    }
    *(float4*)&sDg[r][c*4] = dg4;
    *(float4*)&sRg[r][c*4] = rg4;
  }
  __syncthreads();

  const int x   = tid & 63;
  const int yo0 = (tid >> 6) * 4;   // 4 output rows per thread

  // ================== PASS 1: D image -> nD[4] (MSCN), gD[4] (grad mag) ==================
  float nD[4], gD[4];
  {
    float whg[7]={0,0,0,0,0,0,0}, whq[7]={0,0,0,0,0,0,0};
    float wsx[3]={0,0,0}, wsy[3]={0,0,0};
    #pragma unroll
    for (int st = 0; st < 10; ++st) {
      const int r = yo0 + st;
      float v[7];
      #pragma unroll
      for (int j = 0; j < 7; ++j) v[j] = sDg[r][x+1+j];
      float hg = GW0*(v[0]+v[6]) + GW1*(v[1]+v[5]) + GW2*(v[2]+v[4]) + GW3*v[3];
      float hq = GW0*(v[0]*v[0]+v[6]*v[6]) + GW1*(v[1]*v[1]+v[5]*v[5])
               + GW2*(v[2]*v[2]+v[4]*v[4]) + GW3*v[3]*v[3];
      #pragma unroll
      for (int j = 0; j < 6; ++j) { whg[j]=whg[j+1]; whq[j]=whq[j+1]; }
      whg[6]=hg; whq[6]=hq;
      wsx[0]=wsx[1]; wsx[1]=wsx[2]; wsx[2]=v[2]-v[4];
      wsy[0]=wsy[1]; wsy[1]=wsy[2]; wsy[2]=v[2]+2.f*v[3]+v[4];
      if (st >= 4 && st < 8) {                  // grad for output row st-4
        float gx = wsx[0] + 2.f*wsx[1] + wsx[2];
        float gy = wsy[0] - wsy[2];
        gD[st-4] = SQRTF(gx*gx + gy*gy + EPSF);
      }
      if (st >= 6) {                            // MSCN for output row st-6
        const int k  = st - 6;
        const int ya = yo0 + k;
        float mu = GW0*(whg[0]+whg[6]) + GW1*(whg[1]+whg[5]) + GW2*(whg[2]+whg[4]) + GW3*whg[3];
        float ex = GW0*(whq[0]+whq[6]) + GW1*(whq[1]+whq[5]) + GW2*(whq[2]+whq[4]) + GW3*whq[3];
        float v0 = sDg[ya+HALO][x+4];
        float sig = SQRTF(fabsf(ex - mu*mu + EPSF));
        nD[k] = (v0 - mu) * RCPF(sig + EPSF);
      }
    }
  }

  // ================== PASS 2: R image, combine, accumulate ==================
  float a0 = 0.f, a1 = 0.f, a2 = 0.f;
  {
    float whg[7]={0,0,0,0,0,0,0}, whq[7]={0,0,0,0,0,0,0};
    float wsx[3]={0,0,0}, wsy[3]={0,0,0};
    float grr[2]={0,0};                         // 2-slot grad pipe for R
    #pragma unroll
    for (int st = 0; st < 10; ++st) {
      const int r = yo0 + st;
      float v[7];
      #pragma unroll
      for (int j = 0; j < 7; ++j) v[j] = sRg[r][x+1+j];
      float hg = GW0*(v[0]+v[6]) + GW1*(v[1]+v[5]) + GW2*(v[2]+v[4]) + GW3*v[3];
      float hq = GW0*(v[0]*v[0]+v[6]*v[6]) + GW1*(v[1]*v[1]+v[5]*v[5])
               + GW2*(v[2]*v[2]+v[4]*v[4]) + GW3*v[3]*v[3];
      #pragma unroll
      for (int j = 0; j < 6; ++j) { whg[j]=whg[j+1]; whq[j]=whq[j+1]; }
      whg[6]=hg; whq[6]=hq;
      wsx[0]=wsx[1]; wsx[1]=wsx[2]; wsx[2]=v[2]-v[4];
      wsy[0]=wsy[1]; wsy[1]=wsy[2]; wsy[2]=v[2]+2.f*v[3]+v[4];

      float GRuse = grr[st & 1];                // grad(R) for output st-6 (stored at st-2)

      if (st >= 4 && st < 8) {                  // grad(R) for output st-4
        float gx = wsx[0] + 2.f*wsx[1] + wsx[2];
        float gy = wsy[0] - wsy[2];
        grr[st & 1] = SQRTF(gx*gx + gy*gy + EPSF);
      }

      if (st >= 6) {
        const int k  = st - 6;
        const int ya = yo0 + k;
        float mu = GW0*(whg[0]+whg[6]) + GW1*(whg[1]+whg[5]) + GW2*(whg[2]+whg[4]) + GW3*whg[3];
        float ex = GW0*(whq[0]+whq[6]) + GW1*(whq[1]+whq[5]) + GW2*(whq[2]+whq[4]) + GW3*whq[3];
        float v0 = sRg[ya+HALO][x+4];
        float sig = SQRTF(fabsf(ex - mu*mu + EPSF));
        float Rm = (v0 - mu) * RCPF(sig + EPSF);
        float Dm = nD[k];
        float SM = (2.f*Dm*Rm + CM) * RCPF(Dm*Dm + Rm*Rm + CM);
        float GDv = gD[k];
        float SG = (2.f*GDv*GRuse + CG) * RCPF(GDv*GDv + GRuse*GRuse + CG + EPSF);
        float SDv = sSD[ya][x];
        float SCv = sSC[ya][x];
        float m1 = fabsf(SM * SDv);
        float m2 = SG * SCv;
        float l1 = LOG2F(m1);                   // m1==0 -> -inf -> exp2 -> 0, matches power(0,b)
        float l2 = LOG2F(m2);
        a0 += EXP2F(0.2f*l1 + 0.8f*l2);
        a1 += EXP2F(0.8f*l1 + 0.2f*l2);
        a2 += SQRTF(m1 * m2);                   // == exp2(0.5*(l1+l2)), cheaper
      }
    }
  }

  // ---- block reduce, one atomic per accumulator ----
  #pragma unroll
  for (int o = 32; o > 0; o >>= 1) {
    sdacc += __shfl_down(sdacc, o, 64);
    a0    += __shfl_down(a0,    o, 64);
    a1    += __shfl_down(a1,    o, 64);
    a2    += __shfl_down(a2,    o, 64);
  }
  __shared__ float red[4][4];
  const int w = tid >> 6;
  if ((tid & 63) == 0) { red[w][0]=sdacc; red[w][1]=a0; red[w][2]=a1; red[w][3]=a2; }
  __syncthreads();
  if (tid < 4) {
    float t = red[0][tid]+red[1][tid]+red[2][tid]+red[3][tid];
    if (tid == 0) atomicAdd(sdsum + b, t);
    else          atomicAdd(cand + (tid-1)*NB + b, t);
  }
}

// ---------------- pass 3: select candidate per sample, batch mean ----------------
__global__ void k_final(const float* __restrict__ sdsum, const float* __restrict__ cand,
                        float* __restrict__ out) {
  const int t = threadIdx.x;
  float v = 0.f;
  if (t < NB) {
    float meanSD = sdsum[t] * (1.f/(float)HWPX);
    float c;
    if      (meanSD > 0.85f && meanSD <= 1.0f)  c = cand[0*NB + t];
    else if (meanSD >= 0.f  && meanSD <= 0.85f) c = cand[1*NB + t];
    else                                        c = cand[2*NB + t];
    v = c;
  }
  #pragma unroll
  for (int o = 32; o > 0; o >>= 1) v += __shfl_down(v, o, 64);
  if (t == 0) out[0] = v * (1.f/8388608.f);   // 1/(B*H*W) = 2^-23
}

extern "C" void kernel_launch(void* const* d_in, const int* in_sizes, int n_in,
                              void* d_out, int out_size, void* d_ws, size_t ws_size,
                              hipStream_t stream) {
  (void)in_sizes; (void)n_in; (void)out_size; (void)ws_size;
  const float* D = (const float*)d_in[0];
  const float* R = (const float*)d_in[1];
  float* out = (float*)d_out;
  unsigned* minb  = (unsigned*)d_ws;
  unsigned* maxb  = minb + NB;
  float*    sdsum = (float*)(maxb + NB);
  float*    cand  = sdsum + NB;
  float*    mnp   = cand + 3*NB;
  float*    mxp   = mnp + NB*NCHK;

  k_init  <<<1, 128, 0, stream>>>(sdsum, cand);
  k_minmax<<<dim3(NCHK, NB), 256, 0, stream>>>(D, mnp, mxp);
  k_red   <<<NB, 128, 0, stream>>>(mnp, mxp, minb, maxb);
  k_main  <<<dim3(IMG_W/TW, IMG_H/TH, NB), 256, 0, stream>>>(D, R, minb, maxb, sdsum, cand);
  k_final <<<1, 64, 0, stream>>>(sdsum, cand, out);
}